// Round 2
// baseline (305.851 us; speedup 1.0000x reference)
//
#include <hip/hip_runtime.h>

// Shapes (fixed by the reference): B=4096, V=64, DI=DO=128. All I/O f32.
#define BN 4096
#define VN 64
#define DI 128
#define DO 128

typedef __attribute__((ext_vector_type(8))) short short8;
typedef __attribute__((ext_vector_type(4))) float f32x4;

__device__ __forceinline__ float bf2f(unsigned short s) {
    return __uint_as_float(((unsigned)s) << 16);
}
__device__ __forceinline__ unsigned short f2bf(float f) {   // RNE
    unsigned u = __float_as_uint(f);
    u += 0x7FFF + ((u >> 16) & 1);
    return (unsigned short)(u >> 16);
}
// trunc pack (A-inputs only; h uses RNE)
__device__ __forceinline__ unsigned pack_bf16_trunc(float lo, float hi) {
    return __builtin_amdgcn_perm(__float_as_uint(hi), __float_as_uint(lo), 0x07060302u);
}
__device__ __forceinline__ unsigned pack_bf16_rne(float lo, float hi) {
    return (unsigned)f2bf(lo) | ((unsigned)f2bf(hi) << 16);
}

// h is stored in MFMA C-fragment layout (bf16 units):
//   Hoff(bt,v,w,nt,rt,lane,e) = (((((bt*64+v)*4+w)*4+nt)*4+rt)*64 + lane)*4 + e
// where (w=wm*2+wn, nt, rt) are k_gemm1's tile coords, lane=quad*16+l16,
// e = row-within-quad. Row b = bt*128+wm*64+rt*16+quad*4+e, col o = wn*64+nt*16+l16.
// Each block writes one contiguous 32 KB slab; each wave store = 512 B.

// ---------------------------------------------------------------------------
// Kernel 0: prep. Blocks 0..511: transpose W[v] f32 -> Wt[v] (DOxDI bf16).
// Block 512: adj f32 -> adjbf bf16.
// ---------------------------------------------------------------------------
__global__ __launch_bounds__(256) void k_prep(const float* __restrict__ W,
                                              const float* __restrict__ adj,
                                              unsigned short* __restrict__ Wt,
                                              unsigned short* __restrict__ adjbf) {
    const int t = threadIdx.x, blk = blockIdx.x;
    if (blk < 512) {
        const int v = blk >> 3, q = blk & 7;
        const float* Wv = W + (size_t)v * DI * DO;
        unsigned short* Wtv = Wt + (size_t)v * DI * DO;
        const int o = t & 127;
        const int i0 = q * 16 + (t >> 7) * 8;
        short8 s0;
#pragma unroll
        for (int j = 0; j < 8; ++j)
            s0[j] = (short)f2bf(Wv[(size_t)(i0 + j) * DO + o]);
        *(short8*)(Wtv + o * DI + i0) = s0;
    } else {
        short8 s0, s1;
#pragma unroll
        for (int j = 0; j < 8; ++j) s0[j] = (short)f2bf(adj[t * 16 + j]);
#pragma unroll
        for (int j = 0; j < 8; ++j) s1[j] = (short)f2bf(adj[t * 16 + 8 + j]);
        *(short8*)(adjbf + t * 16) = s0;
        *(short8*)(adjbf + t * 16 + 8) = s1;
    }
}

// ---------------------------------------------------------------------------
// Kernel 1: grouped GEMM h = feat @ W[v] + b[v], 128x128 tile, bf16 MFMA.
// R1 result: occupancy 25->35% changed NOTHING (dur 81.4us, 1.72 TB/s both
// rounds) -> not wave-starved; HBM pipe is the wall (likely shared with the
// harness poison-fill L3 write-back drain). Left unchanged this round.
// ---------------------------------------------------------------------------
__global__ __launch_bounds__(256, 4) void k_gemm1(const float* __restrict__ feat,
                                                  const unsigned short* __restrict__ Wt,
                                                  const float* __restrict__ bias,
                                                  unsigned short* __restrict__ h,
                                                  float* __restrict__ psA,
                                                  float* __restrict__ psB) {
    const int v = blockIdx.x;
    const int bt = blockIdx.y;
    const int tid = threadIdx.x;
    const int w = tid >> 6, lane = tid & 63;
    const int wm = w >> 1, wn = w & 1;
    const int quad = lane >> 4, l16 = lane & 15;

    // 32-bit element offsets: feat has 4096*64*128 = 33.5M floats < 2^32
    unsigned aidx[4];
#pragma unroll
    for (int rt = 0; rt < 4; ++rt)
        aidx[rt] = (unsigned)(bt * 128 + wm * 64 + rt * 16 + l16) * (VN * DI)
                 + (unsigned)(v * DI + quad * 8);

    // B-fragment base for this thread; fragment (ks,nt) = wbase + nt*16*DI + ks*32
    const unsigned short* wbase = Wt + (size_t)v * (DI * DO)
                                + (size_t)(wn * 64 + l16) * DI + quad * 8;

    f32x4 acc[4][4];
#pragma unroll
    for (int rt = 0; rt < 4; ++rt)
#pragma unroll
        for (int nt = 0; nt < 4; ++nt) acc[rt][nt] = (f32x4){0.f, 0.f, 0.f, 0.f};

#define LOADA(dst, k0)                                                        \
    {                                                                         \
        _Pragma("unroll") for (int rt = 0; rt < 4; ++rt) {                    \
            f32x4 f0 = *(const f32x4*)(feat + aidx[rt] + (k0));               \
            f32x4 f1 = *(const f32x4*)(feat + aidx[rt] + (k0) + 4);          \
            union { short8 s; unsigned u[4]; } pk;                            \
            pk.u[0] = pack_bf16_trunc(f0[0], f0[1]);                          \
            pk.u[1] = pack_bf16_trunc(f0[2], f0[3]);                          \
            pk.u[2] = pack_bf16_trunc(f1[0], f1[1]);                          \
            pk.u[3] = pack_bf16_trunc(f1[2], f1[3]);                          \
            dst[rt] = pk.s;                                                   \
        }                                                                     \
    }

    short8 aCur[4], aNxt[4], bb[4];
    LOADA(aCur, 0)
#pragma unroll
    for (int ks = 0; ks < 4; ++ks) {
        // B fragments for this K-slice only (16 regs live, L2-hot reload)
#pragma unroll
        for (int nt = 0; nt < 4; ++nt)
            bb[nt] = *(const short8*)(wbase + nt * (16 * DI) + ks * 32);
        if (ks < 3) LOADA(aNxt, (ks + 1) * 32)
#pragma unroll
        for (int rt = 0; rt < 4; ++rt)
#pragma unroll
            for (int nt = 0; nt < 4; ++nt)
                acc[rt][nt] = __builtin_amdgcn_mfma_f32_16x16x32_bf16(
                    aCur[rt], bb[nt], acc[rt][nt], 0, 0, 0);
        if (ks < 3) {
#pragma unroll
            for (int rt = 0; rt < 4; ++rt) aCur[rt] = aNxt[rt];
        }
    }
#undef LOADA

    // epilogue: +bias, BN partials (race-free), fragment-layout h stores
    unsigned short* hblk = h + ((size_t)(bt * 64 + v) * 4 + w) * 4096;
#pragma unroll
    for (int nt = 0; nt < 4; ++nt) {
        const int col = wn * 64 + nt * 16 + l16;
        const float bv = bias[v * DO + col];
        float s = 0.f, sq = 0.f;
#pragma unroll
        for (int rt = 0; rt < 4; ++rt)
#pragma unroll
            for (int e = 0; e < 4; ++e) {
                float x = acc[rt][nt][e] + bv;
                acc[rt][nt][e] = x;
                s += x;
                sq += x * x;
            }
        s += __shfl_down(s, 32);  s += __shfl_down(s, 16);
        sq += __shfl_down(sq, 32); sq += __shfl_down(sq, 16);
        if (lane < 16) {
            const size_t pi = ((size_t)(v * 32 + bt) * 2 + wm) * 128 + col;
            psA[pi] = s;
            psB[pi] = sq;
        }
#pragma unroll
        for (int rt = 0; rt < 4; ++rt) {
            uint2 pk;
            pk.x = pack_bf16_rne(acc[rt][nt][0], acc[rt][nt][1]);
            pk.y = pack_bf16_rne(acc[rt][nt][2], acc[rt][nt][3]);
            *(uint2*)(hblk + (size_t)((nt * 4 + rt) * 64 + lane) * 4) = pk;
        }
    }
}

// ---------------------------------------------------------------------------
// Kernel 2a: reduce partials -> scale, shift. 64 blocks (v).
// ---------------------------------------------------------------------------
__global__ __launch_bounds__(128) void k_reduce(const float* __restrict__ psA,
                                                const float* __restrict__ psB,
                                                const float* __restrict__ gamma,
                                                const float* __restrict__ beta,
                                                float* __restrict__ scale,
                                                float* __restrict__ shift) {
    const int o = threadIdx.x;
    const int v = blockIdx.x;
    float s = 0.f, sq = 0.f;
#pragma unroll
    for (int p = 0; p < 64; ++p) {
        const size_t pi = ((size_t)v * 64 + p) * 128 + o;
        s += psA[pi];
        sq += psB[pi];
    }
    const float invB = 1.0f / (float)BN;
    const float mu = s * invB;
    const float var = sq * invB - mu * mu;
    const float sc = gamma[v * DO + o] * rsqrtf(var + 1e-5f);
    scale[v * DO + o] = sc;
    shift[v * DO + o] = beta[v * DO + o] - mu * sc;
}

// ---------------------------------------------------------------------------
// Kernel 2b: C0[u,o] = sum_v adj[u,v] * shift[v,o]. 64 blocks (u).
// ---------------------------------------------------------------------------
__global__ __launch_bounds__(128) void k_c0(const float* __restrict__ adj,
                                            const float* __restrict__ shift,
                                            float* __restrict__ C0) {
    const int o = threadIdx.x;
    const int u = blockIdx.x;
    float c0 = 0.f;
#pragma unroll
    for (int v = 0; v < VN; ++v)
        c0 += adj[u * VN + v] * shift[v * DO + o];
    C0[u * DO + o] = c0;
}

// ---------------------------------------------------------------------------
// Kernel 3 (MFMA mix): out[b,u,o] = relu( sum_v adj[u,v]*(h[b,v,o]*scale[v,o])
//                                         + C0[u,o] )
// R2 rewrite: operands SWAPPED vs previous round. Now D[row=o][col=u] with
//   A = hsT (row=o, k=v)  and  B = adj^T (col=u, k=v) = adjbf[u][v] row-major.
// C-fragment e-index walks o (contiguous in out), so:
//   out stores: 16 x f32x4 (was 64 x 4B scalars)
//   C0 loads:   16 x f32x4 (was 64 scalars)
//   h loads:    16 x uint4 covering (o,o+1) (was 32 x uint2)
//   LDS stage:  16 x ds_write_b64 (4-v groups) (was 64 x ds_write_b16)
// Numerically bit-identical to previous version (same MFMA shape, same
// k-chaining order over v, same operand values).
// ---------------------------------------------------------------------------
__global__ __launch_bounds__(512, 4) void k_mix(const unsigned short* __restrict__ h,
                                                const float* __restrict__ scale,
                                                const unsigned short* __restrict__ adjbf,
                                                const float* __restrict__ C0,
                                                float* __restrict__ out) {
    __shared__ unsigned short hsT[4][DO][72];   // 73,728 B (pad 72: 144B rows, 16B-aligned)
    const int t = threadIdx.x;
    const int b0 = blockIdx.x * 4;
    const int bt = b0 >> 7;
    const int r = b0 & 127;
    const int swm = r >> 6, srt = (r >> 4) & 3, squad = (r >> 2) & 3;

    // stage: 2 iters; each thread owns 4 v (v0..v0+3) x 2 o (o0,o0+1) x 4 e.
    // uint4 h load covers both o's (16B aligned: o0 even). ds_write_b64 per
    // (e, o): 4 v-consecutive bf16.
#pragma unroll
    for (int c = 0; c < 2; ++c) {
        const int g = c * 512 + t;            // 0..1023
        const int o0 = (g & 63) * 2;
        const int v0 = (g >> 6) * 4;
        union { unsigned long long q; unsigned short s[4]; } rA[4], rB[4];
#pragma unroll
        for (int i = 0; i < 4; ++i) {
            const int v = v0 + i;
            const size_t off = (size_t)(bt * 64 + v) * 16384
                             + (size_t)(((swm * 2 + (o0 >> 6)) * 4 + ((o0 >> 4) & 3)) * 4 + srt) * 256
                             + (size_t)(squad * 16 + (o0 & 15)) * 4;
            const uint4 pk = *(const uint4*)(h + off);
            const float2 sc = *(const float2*)(scale + v * DO + o0);
            rA[0].s[i] = f2bf(bf2f((unsigned short)(pk.x & 0xFFFF)) * sc.x);
            rA[1].s[i] = f2bf(bf2f((unsigned short)(pk.x >> 16)) * sc.x);
            rA[2].s[i] = f2bf(bf2f((unsigned short)(pk.y & 0xFFFF)) * sc.x);
            rA[3].s[i] = f2bf(bf2f((unsigned short)(pk.y >> 16)) * sc.x);
            rB[0].s[i] = f2bf(bf2f((unsigned short)(pk.z & 0xFFFF)) * sc.y);
            rB[1].s[i] = f2bf(bf2f((unsigned short)(pk.z >> 16)) * sc.y);
            rB[2].s[i] = f2bf(bf2f((unsigned short)(pk.w & 0xFFFF)) * sc.y);
            rB[3].s[i] = f2bf(bf2f((unsigned short)(pk.w >> 16)) * sc.y);
        }
#pragma unroll
        for (int e = 0; e < 4; ++e) {
            *(unsigned long long*)&hsT[e][o0][v0]     = rA[e].q;
            *(unsigned long long*)&hsT[e][o0 + 1][v0] = rB[e].q;
        }
    }
    __syncthreads();

    const int w = t >> 6, lane = t & 63;
    const int bl = w >> 1, nh = w & 1;      // bl: batch sub-elem, nh: o-half
    const int quad = lane >> 4, l16 = lane & 15;
    const int b = b0 + bl;

    // B = adj^T fragments: col=u=nt*16+l16, k=v=ks*32+quad*8+j -> adjbf[u][v]
    short8 bfr[4][2];
#pragma unroll
    for (int nt = 0; nt < 4; ++nt)
#pragma unroll
        for (int ks = 0; ks < 2; ++ks)
            bfr[nt][ks] = *(const short8*)(adjbf + (nt * 16 + l16) * VN
                                           + ks * 32 + quad * 8);

    f32x4 acc[4][4];
#pragma unroll
    for (int mt = 0; mt < 4; ++mt)
#pragma unroll
        for (int nt = 0; nt < 4; ++nt) acc[mt][nt] = (f32x4){0.f, 0.f, 0.f, 0.f};

#pragma unroll
    for (int mt = 0; mt < 4; ++mt) {
        // A = hsT: row=o=nh*64+mt*16+l16, k=v=ks*32+quad*8+j
        const unsigned short* ap = &hsT[bl][nh * 64 + mt * 16 + l16][quad * 8];
        short8 a0 = *(const short8*)(ap);
        short8 a1 = *(const short8*)(ap + 32);
#pragma unroll
        for (int nt = 0; nt < 4; ++nt) {
            acc[mt][nt] = __builtin_amdgcn_mfma_f32_16x16x32_bf16(
                a0, bfr[nt][0], acc[mt][nt], 0, 0, 0);
            acc[mt][nt] = __builtin_amdgcn_mfma_f32_16x16x32_bf16(
                a1, bfr[nt][1], acc[mt][nt], 0, 0, 0);
        }
    }

    // epilogue: D[row=o][col=u]; e walks o -> f32x4 stores along o
#pragma unroll
    for (int mt = 0; mt < 4; ++mt) {
        const int ob = nh * 64 + mt * 16 + quad * 4;
#pragma unroll
        for (int nt = 0; nt < 4; ++nt) {
            const int u = nt * 16 + l16;
            const f32x4 c0v = *(const f32x4*)(C0 + u * DO + ob);
            f32x4 rr;
#pragma unroll
            for (int e = 0; e < 4; ++e)
                rr[e] = fmaxf(acc[mt][nt][e] + c0v[e], 0.0f);
            *(f32x4*)(out + ((size_t)b * VN + u) * DO + ob) = rr;
        }
    }
}

// ---------------------------------------------------------------------------
extern "C" void kernel_launch(void* const* d_in, const int* in_sizes, int n_in,
                              void* d_out, int out_size, void* d_ws, size_t ws_size,
                              hipStream_t stream) {
    const float* feat  = (const float*)d_in[0];
    const float* adj   = (const float*)d_in[1];
    const float* W     = (const float*)d_in[2];
    const float* bias  = (const float*)d_in[3];
    const float* gamma = (const float*)d_in[4];
    const float* beta  = (const float*)d_in[5];
    float* out = (float*)d_out;

    char* ws = (char*)d_ws;
    unsigned short* h     = (unsigned short*)ws;                 // 67,108,864 B
    unsigned short* Wt    = (unsigned short*)(ws + 67108864ull); //  2,097,152 B
    unsigned short* adjbf = (unsigned short*)(ws + 69206016ull); //      8,192 B
    float* psA   = (float*)(ws + 69214208ull);                   //  2 MiB
    float* psB   = psA + 524288;                                 //  2 MiB
    float* scale = psB + 524288;                                 // 32 KiB
    float* shift = scale + 8192;                                 // 32 KiB
    float* C0    = shift + 8192;                                 // 32 KiB

    k_prep<<<dim3(513), dim3(256), 0, stream>>>(W, adj, Wt, adjbf);
    k_gemm1<<<dim3(64, 32), dim3(256), 0, stream>>>(feat, Wt, bias, h, psA, psB);
    k_reduce<<<dim3(64), dim3(128), 0, stream>>>(psA, psB, gamma, beta, scale, shift);
    k_c0<<<dim3(64), dim3(128), 0, stream>>>(adj, shift, C0);
    k_mix<<<dim3(1024), dim3(512), 0, stream>>>(h, scale, adjbf, C0, out);
}

// Round 3
// 286.055 us; speedup vs baseline: 1.0692x; 1.0692x over previous
//
#include <hip/hip_runtime.h>

// Shapes (fixed by the reference): B=4096, V=64, DI=DO=128. All I/O f32.
#define BN 4096
#define VN 64
#define DI 128
#define DO 128

typedef __attribute__((ext_vector_type(8))) short short8;
typedef __attribute__((ext_vector_type(4))) float f32x4;

__device__ __forceinline__ float bf2f(unsigned short s) {
    return __uint_as_float(((unsigned)s) << 16);
}
__device__ __forceinline__ unsigned short f2bf(float f) {   // RNE
    unsigned u = __float_as_uint(f);
    u += 0x7FFF + ((u >> 16) & 1);
    return (unsigned short)(u >> 16);
}
// trunc pack (A-inputs only; h uses RNE)
__device__ __forceinline__ unsigned pack_bf16_trunc(float lo, float hi) {
    return __builtin_amdgcn_perm(__float_as_uint(hi), __float_as_uint(lo), 0x07060302u);
}
__device__ __forceinline__ unsigned pack_bf16_rne(float lo, float hi) {
    return (unsigned)f2bf(lo) | ((unsigned)f2bf(hi) << 16);
}

// h is stored in MFMA C-fragment layout (bf16 units):
//   Hoff(bt,v,w,nt,rt,lane,e) = (((((bt*64+v)*4+w)*4+nt)*4+rt)*64 + lane)*4 + e
// where (w=wm*2+wn, nt, rt) are k_gemm1's tile coords, lane=quad*16+l16,
// e = row-within-quad. Row b = bt*128+wm*64+rt*16+quad*4+e, col o = wn*64+nt*16+l16.
// Each block writes one contiguous 32 KB slab; each wave store = 512 B.

// ---------------------------------------------------------------------------
// Kernel 0: prep. Blocks 0..511: transpose W[v] f32 -> Wt[v] (DOxDI bf16).
// Block 512: adj f32 -> adjbf bf16.
// ---------------------------------------------------------------------------
__global__ __launch_bounds__(256) void k_prep(const float* __restrict__ W,
                                              const float* __restrict__ adj,
                                              unsigned short* __restrict__ Wt,
                                              unsigned short* __restrict__ adjbf) {
    const int t = threadIdx.x, blk = blockIdx.x;
    if (blk < 512) {
        const int v = blk >> 3, q = blk & 7;
        const float* Wv = W + (size_t)v * DI * DO;
        unsigned short* Wtv = Wt + (size_t)v * DI * DO;
        const int o = t & 127;
        const int i0 = q * 16 + (t >> 7) * 8;
        short8 s0;
#pragma unroll
        for (int j = 0; j < 8; ++j)
            s0[j] = (short)f2bf(Wv[(size_t)(i0 + j) * DO + o]);
        *(short8*)(Wtv + o * DI + i0) = s0;
    } else {
        short8 s0, s1;
#pragma unroll
        for (int j = 0; j < 8; ++j) s0[j] = (short)f2bf(adj[t * 16 + j]);
#pragma unroll
        for (int j = 0; j < 8; ++j) s1[j] = (short)f2bf(adj[t * 16 + 8 + j]);
        *(short8*)(adjbf + t * 16) = s0;
        *(short8*)(adjbf + t * 16 + 8) = s1;
    }
}

// ---------------------------------------------------------------------------
// Kernel 1: grouped GEMM h = feat @ W[v] + b[v], 128x128 tile, bf16 MFMA.
// R3 rewrite: feat tile staged to LDS via global_load_lds (width 16, zero
// VGPR staging). R0-R2 evidence: VGPR-staged global loads serialize
// (load->wait->pack per pair), exposing multiple HBM latencies per K-step
// -> 1.7 TB/s, occupancy-insensitive. Now: 64 DMA wave-instructions + 16
// up-front L2-hot Wt loads issued back-to-back, ONE vmcnt(0) drain at the
// barrier, then fully on-chip MFMA loop. In-flight/CU ~128 KB >> 9 KB needed
// for 6.3 TB/s. LDS 64 KB -> 2 blocks/CU (latency hidden by DMA depth, not
// occupancy). LDS XOR-chunk swizzle (pos = chunk ^ (row&7)) applied via
// pre-swizzled GLOBAL source (gload_lds dest must stay linear), unswizzled
// on the ds_read side -> conflict-free-floor b128 reads.
// ---------------------------------------------------------------------------
__global__ __launch_bounds__(256) void k_gemm1(const float* __restrict__ feat,
                                               const unsigned short* __restrict__ Wt,
                                               const float* __restrict__ bias,
                                               unsigned short* __restrict__ h,
                                               float* __restrict__ psA,
                                               float* __restrict__ psB) {
    __shared__ float ldsA[128 * 128];   // 65,536 B feat tile (swizzled chunks)
    const int v = blockIdx.x;
    const int bt = blockIdx.y;
    const int tid = threadIdx.x;
    const int w = tid >> 6, lane = tid & 63;
    const int wm = w >> 1, wn = w & 1;
    const int quad = lane >> 4, l16 = lane & 15;

    // --- up-front B fragments (L2-hot: XCD = v%8 for all bt) ---
    const unsigned short* wbase = Wt + (size_t)v * (DI * DO)
                                + (size_t)(wn * 64 + l16) * DI + quad * 8;
    short8 bb[4][4];
#pragma unroll
    for (int ks = 0; ks < 4; ++ks)
#pragma unroll
        for (int nt = 0; nt < 4; ++nt)
            bb[ks][nt] = *(const short8*)(wbase + nt * (16 * DI) + ks * 32);

    // --- stage feat tile: wave w stages rows [w*32, w*32+32) ---
    // DMA writes linear: ldsbase + lane*16B. lane l -> row=2i+(l>>5),
    // chunk-position p=(l&31). Position p at row r holds global 16B-chunk
    // c = p ^ (r&7)  (read side XORs the same way).
    {
        const int lrow = lane >> 5;          // 0..1
        const int lpos = lane & 31;          // chunk position 0..31
#pragma unroll
        for (int i = 0; i < 16; ++i) {
            const int row = w * 32 + 2 * i + lrow;
            const int gchunk = lpos ^ (row & 7);
            const float* src = feat + (size_t)(bt * 128 + row) * (VN * DI)
                             + v * DI + gchunk * 4;
            float* dst = &ldsA[(w * 32 + 2 * i) * 128];
            __builtin_amdgcn_global_load_lds(
                (const __attribute__((address_space(1))) void*)src,
                (__attribute__((address_space(3))) void*)dst, 16, 0, 0);
        }
    }
    __syncthreads();   // one vmcnt(0) drain: bb + all DMA arrive together

    f32x4 acc[4][4];
#pragma unroll
    for (int rt = 0; rt < 4; ++rt)
#pragma unroll
        for (int nt = 0; nt < 4; ++nt) acc[rt][nt] = (f32x4){0.f, 0.f, 0.f, 0.f};

#pragma unroll
    for (int ks = 0; ks < 4; ++ks) {
        short8 aCur[4];
#pragma unroll
        for (int rt = 0; rt < 4; ++rt) {
            const int row = wm * 64 + rt * 16 + l16;
            const int xr = row & 7;
            const int c0 = ks * 8 + quad * 2;
            const f32x4 f0 = *(const f32x4*)&ldsA[row * 128 + ((c0    ) ^ xr) * 4];
            const f32x4 f1 = *(const f32x4*)&ldsA[row * 128 + ((c0 + 1) ^ xr) * 4];
            union { short8 s; unsigned u[4]; } pk;
            pk.u[0] = pack_bf16_trunc(f0[0], f0[1]);
            pk.u[1] = pack_bf16_trunc(f0[2], f0[3]);
            pk.u[2] = pack_bf16_trunc(f1[0], f1[1]);
            pk.u[3] = pack_bf16_trunc(f1[2], f1[3]);
            aCur[rt] = pk.s;
        }
#pragma unroll
        for (int rt = 0; rt < 4; ++rt)
#pragma unroll
            for (int nt = 0; nt < 4; ++nt)
                acc[rt][nt] = __builtin_amdgcn_mfma_f32_16x16x32_bf16(
                    aCur[rt], bb[ks][nt], acc[rt][nt], 0, 0, 0);
    }

    // epilogue: +bias, BN partials (race-free), fragment-layout h stores
    unsigned short* hblk = h + ((size_t)(bt * 64 + v) * 4 + w) * 4096;
#pragma unroll
    for (int nt = 0; nt < 4; ++nt) {
        const int col = wn * 64 + nt * 16 + l16;
        const float bv = bias[v * DO + col];
        float s = 0.f, sq = 0.f;
#pragma unroll
        for (int rt = 0; rt < 4; ++rt)
#pragma unroll
            for (int e = 0; e < 4; ++e) {
                float x = acc[rt][nt][e] + bv;
                acc[rt][nt][e] = x;
                s += x;
                sq += x * x;
            }
        s += __shfl_down(s, 32);  s += __shfl_down(s, 16);
        sq += __shfl_down(sq, 32); sq += __shfl_down(sq, 16);
        if (lane < 16) {
            const size_t pi = ((size_t)(v * 32 + bt) * 2 + wm) * 128 + col;
            psA[pi] = s;
            psB[pi] = sq;
        }
#pragma unroll
        for (int rt = 0; rt < 4; ++rt) {
            uint2 pk;
            pk.x = pack_bf16_rne(acc[rt][nt][0], acc[rt][nt][1]);
            pk.y = pack_bf16_rne(acc[rt][nt][2], acc[rt][nt][3]);
            *(uint2*)(hblk + (size_t)((nt * 4 + rt) * 64 + lane) * 4) = pk;
        }
    }
}

// ---------------------------------------------------------------------------
// Kernel 2a: reduce partials -> scale, shift. 64 blocks (v).
// ---------------------------------------------------------------------------
__global__ __launch_bounds__(128) void k_reduce(const float* __restrict__ psA,
                                                const float* __restrict__ psB,
                                                const float* __restrict__ gamma,
                                                const float* __restrict__ beta,
                                                float* __restrict__ scale,
                                                float* __restrict__ shift) {
    const int o = threadIdx.x;
    const int v = blockIdx.x;
    float s = 0.f, sq = 0.f;
#pragma unroll
    for (int p = 0; p < 64; ++p) {
        const size_t pi = ((size_t)v * 64 + p) * 128 + o;
        s += psA[pi];
        sq += psB[pi];
    }
    const float invB = 1.0f / (float)BN;
    const float mu = s * invB;
    const float var = sq * invB - mu * mu;
    const float sc = gamma[v * DO + o] * rsqrtf(var + 1e-5f);
    scale[v * DO + o] = sc;
    shift[v * DO + o] = beta[v * DO + o] - mu * sc;
}

// ---------------------------------------------------------------------------
// Kernel 2b: C0[u,o] = sum_v adj[u,v] * shift[v,o]. 64 blocks (u).
// ---------------------------------------------------------------------------
__global__ __launch_bounds__(128) void k_c0(const float* __restrict__ adj,
                                            const float* __restrict__ shift,
                                            float* __restrict__ C0) {
    const int o = threadIdx.x;
    const int u = blockIdx.x;
    float c0 = 0.f;
#pragma unroll
    for (int v = 0; v < VN; ++v)
        c0 += adj[u * VN + v] * shift[v * DO + o];
    C0[u * DO + o] = c0;
}

// ---------------------------------------------------------------------------
// Kernel 3 (MFMA mix): out[b,u,o] = relu( sum_v adj[u,v]*(h[b,v,o]*scale[v,o])
//                                         + C0[u,o] )
// R3: REVERTED to the R0/R1 version. The R2 operand-swapped rewrite
// regressed ~10 us (295.5 -> 305.9 total, gemm1/fills flat) -- likely the
// 8-way bank conflicts on b64 stage writes. Known-good baseline restored.
// ---------------------------------------------------------------------------
__global__ __launch_bounds__(512, 4) void k_mix(const unsigned short* __restrict__ h,
                                                const float* __restrict__ scale,
                                                const unsigned short* __restrict__ adjbf,
                                                const float* __restrict__ C0,
                                                float* __restrict__ out) {
    __shared__ unsigned short hsT[4][DO][72];   // 73,728 B
    const int t = threadIdx.x;
    const int b0 = blockIdx.x * 4;
    const int bt = b0 >> 7;
    const int r = b0 & 127;
    const int swm = r >> 6, srt = (r >> 4) & 3, squad = (r >> 2) & 3;

    // stage: 16 iters x 512 threads = 8192 (v,o) pairs, 8 B each
#pragma unroll
    for (int c = 0; c < 16; ++c) {
        const int p = c * 512 + t;
        const int v = p >> 7, o = p & 127;
        const size_t off = (size_t)(bt * 64 + v) * 16384
                         + (size_t)(((swm * 2 + (o >> 6)) * 4 + ((o >> 4) & 3)) * 4 + srt) * 256
                         + (size_t)(squad * 16 + (o & 15)) * 4;
        const uint2 pk = *(const uint2*)(h + off);
        const float sc = scale[v * DO + o];
        hsT[0][o][v] = f2bf(bf2f((unsigned short)(pk.x & 0xFFFF)) * sc);
        hsT[1][o][v] = f2bf(bf2f((unsigned short)(pk.x >> 16)) * sc);
        hsT[2][o][v] = f2bf(bf2f((unsigned short)(pk.y & 0xFFFF)) * sc);
        hsT[3][o][v] = f2bf(bf2f((unsigned short)(pk.y >> 16)) * sc);
    }
    __syncthreads();

    const int w = t >> 6, lane = t & 63;
    const int bl = w >> 1, nh = w & 1;
    const int quad = lane >> 4, l16 = lane & 15;
    const int b = b0 + bl;

    short8 af[4][2];
#pragma unroll
    for (int mt = 0; mt < 4; ++mt)
#pragma unroll
        for (int ks = 0; ks < 2; ++ks)
            af[mt][ks] = *(const short8*)(adjbf + (mt * 16 + l16) * VN
                                          + ks * 32 + quad * 8);

    f32x4 acc[4][4];
#pragma unroll
    for (int mt = 0; mt < 4; ++mt)
#pragma unroll
        for (int nt = 0; nt < 4; ++nt) acc[mt][nt] = (f32x4){0.f, 0.f, 0.f, 0.f};

#pragma unroll
    for (int nt = 0; nt < 4; ++nt) {
        const unsigned short* bp = &hsT[bl][nh * 64 + nt * 16 + l16][quad * 8];
        short8 bf0 = *(const short8*)(bp);
        short8 bf1 = *(const short8*)(bp + 32);
#pragma unroll
        for (int mt = 0; mt < 4; ++mt) {
            acc[mt][nt] = __builtin_amdgcn_mfma_f32_16x16x32_bf16(
                af[mt][0], bf0, acc[mt][nt], 0, 0, 0);
            acc[mt][nt] = __builtin_amdgcn_mfma_f32_16x16x32_bf16(
                af[mt][1], bf1, acc[mt][nt], 0, 0, 0);
        }
    }

#pragma unroll
    for (int mt = 0; mt < 4; ++mt)
#pragma unroll
        for (int nt = 0; nt < 4; ++nt) {
            const int o = nh * 64 + nt * 16 + l16;
#pragma unroll
            for (int e = 0; e < 4; ++e) {
                const int u = mt * 16 + quad * 4 + e;
                out[((size_t)b * VN + u) * DO + o] =
                    fmaxf(acc[mt][nt][e] + C0[u * DO + o], 0.0f);
            }
        }
}

// ---------------------------------------------------------------------------
extern "C" void kernel_launch(void* const* d_in, const int* in_sizes, int n_in,
                              void* d_out, int out_size, void* d_ws, size_t ws_size,
                              hipStream_t stream) {
    const float* feat  = (const float*)d_in[0];
    const float* adj   = (const float*)d_in[1];
    const float* W     = (const float*)d_in[2];
    const float* bias  = (const float*)d_in[3];
    const float* gamma = (const float*)d_in[4];
    const float* beta  = (const float*)d_in[5];
    float* out = (float*)d_out;

    char* ws = (char*)d_ws;
    unsigned short* h     = (unsigned short*)ws;                 // 67,108,864 B
    unsigned short* Wt    = (unsigned short*)(ws + 67108864ull); //  2,097,152 B
    unsigned short* adjbf = (unsigned short*)(ws + 69206016ull); //      8,192 B
    float* psA   = (float*)(ws + 69214208ull);                   //  2 MiB
    float* psB   = psA + 524288;                                 //  2 MiB
    float* scale = psB + 524288;                                 // 32 KiB
    float* shift = scale + 8192;                                 // 32 KiB
    float* C0    = shift + 8192;                                 // 32 KiB

    k_prep<<<dim3(513), dim3(256), 0, stream>>>(W, adj, Wt, adjbf);
    k_gemm1<<<dim3(64, 32), dim3(256), 0, stream>>>(feat, Wt, bias, h, psA, psB);
    k_reduce<<<dim3(64), dim3(128), 0, stream>>>(psA, psB, gamma, beta, scale, shift);
    k_c0<<<dim3(64), dim3(128), 0, stream>>>(adj, shift, C0);
    k_mix<<<dim3(1024), dim3(512), 0, stream>>>(h, scale, adjbf, C0, out);
}